// Round 17
// baseline (39.379 us; speedup 1.0000x reference)
//
#include <hip/hip_runtime.h>
#include <hip/hip_bf16.h>

#define TOKENS 16384
#define NEXP 8
#define INF 512
#define OUTF 512

#define BM 128
#define BN 128
#define BK 32
#define NST (INF / BK)     // 16 K-steps
#define MAXMT 20           // 2560 rows/expert; counts ~2048±42(σ) -> +12σ safe
#define EROWS (MAXMT * BM)
#define SLOTA (BM * BK * 2)   // 8 KB bf16 A per ring slot
#define SLOTB (BN * BK * 2)   // 8 KB bf16 B per ring slot

using f32x4 = __attribute__((ext_vector_type(4))) float;
using bfrag = __attribute__((ext_vector_type(8))) __bf16;
using s8v   = __attribute__((ext_vector_type(8))) short;

// fp32 -> bf16 RNE
__device__ __forceinline__ short f2bf(float f) {
  union { float f; unsigned u; } v; v.f = f;
  unsigned r = v.u + 0x7fffu + ((v.u >> 16) & 1u);
  return (short)(r >> 16);
}

__device__ __forceinline__ void gload16(const void* g, void* l) {
  __builtin_amdgcn_global_load_lds(
      (const __attribute__((address_space(1))) unsigned int*)g,
      (__attribute__((address_space(3))) unsigned int*)l, 16, 0, 0);
}

__device__ __forceinline__ s8v pack8(float4 a, float4 b) {
  s8v p;
  p[0] = f2bf(a.x); p[1] = f2bf(a.y); p[2] = f2bf(a.z); p[3] = f2bf(a.w);
  p[4] = f2bf(b.x); p[5] = f2bf(b.y); p[6] = f2bf(b.z); p[7] = f2bf(b.w);
  return p;
}

// Fused prep (cursor pre-zeroed by memsetAsync):
//   blocks 0..63      : scatter tokens by expert (block-aggregated atomics)
//   blocks 64..1087   : weight fp32 -> bf16  (wbf, [E][O][I] contiguous)
//   blocks 1088..5183 : inp fp32 -> bf16     (inpb, TOKEN ORDER — no gather)
__global__ void k_prep(const int* __restrict__ gate, int* __restrict__ cursor,
                       int* __restrict__ perm, const float* __restrict__ w,
                       s8v* __restrict__ wb, const float* __restrict__ inp,
                       s8v* __restrict__ inpb) {
  __shared__ int lc[NEXP], lb[NEXP];
  const int bid = blockIdx.x, tid = threadIdx.x;
  if (bid < 64) {
    if (tid < NEXP) lc[tid] = 0;
    __syncthreads();
    int t = bid * 256 + tid;
    int e = gate[t];
    int ls = atomicAdd(&lc[e], 1);
    __syncthreads();
    if (tid < NEXP) lb[tid] = lc[tid] ? atomicAdd(&cursor[tid], lc[tid]) : 0;
    __syncthreads();
    perm[e * EROWS + lb[e] + ls] = t;
  } else if (bid < 1088) {
    int idx = (bid - 64) * 256 + tid;
    const float4* src = (const float4*)w + (size_t)idx * 2;
    wb[idx] = pack8(src[0], src[1]);
  } else {
    int idx = (bid - 1088) * 256 + tid;        // 4096 blocks, exact cover
    const float4* src = (const float4*)inp + (size_t)idx * 2;
    inpb[idx] = pack8(src[0], src[1]);
  }
}

#define KBAR(N)                                                         \
  asm volatile("s_waitcnt vmcnt(" #N ") lgkmcnt(0)" ::: "memory");      \
  __builtin_amdgcn_sched_barrier(0);                                    \
  __builtin_amdgcn_s_barrier();                                         \
  __builtin_amdgcn_sched_barrier(0);

// Grouped GEMM — minimum staged bytes (134 MB: 128² tile, both operands bf16)
// + R8-proven homogeneous ring-3 counted-vmcnt schedule (no per-step drain —
// the combination R15 lacked). Per step t: DMA(t+2) [4 gload16]; COMP(t)
// [16 MFMA]; KBAR(4) retires DMA(t+1) with ~2 COMPs of slack, DMA(t+2) rides
// across. Slot-reuse invariant (R8): DMA(t+2) writes slot (t+2)%3=(t-1)%3,
// whose COMP(t-1) reads finished before step t-1's KBAR (lgkmcnt(0)+barrier).
// bid = e + 8*(nt + 4*mt): e -> XCD (B_e L2-hot); nt-siblings share A in L2.
// A & B identical staging geometry (2 sites each, 8 chunks/row of 16B),
// swizzle both-sides clog = c ^ (row&7) (proven R4/R11/R14/R15).
__global__ __launch_bounds__(256, 2)
void moe_gemm11(const short* __restrict__ inpb, const short* __restrict__ wbf,
                const int* __restrict__ cursor, const int* __restrict__ perm,
                float* __restrict__ out) {
  const int bid = blockIdx.x;
  const int e  = bid & 7;
  const int nt = (bid >> 3) & 3;
  const int mt = bid >> 5;
  const int cnt = cursor[e];
  if (mt * BM >= cnt) return;
  const int m_valid = min(BM, cnt - mt * BM);
  const int* pb = perm + e * EROWS + mt * BM;

  __shared__ __align__(16) char Albs[3][SLOTA];   // 3 x 8 KB
  __shared__ __align__(16) char Blbs[3][SLOTB];   // 3 x 8 KB
  __shared__ int toks[BM];

  const int tid = threadIdx.x;
  if (tid < BM) toks[tid] = pb[(tid < m_valid) ? tid : 0];
  __syncthreads();

  const int lane = tid & 63;
  const int wid  = tid >> 6;
  const int wr = wid >> 1, wc = wid & 1;   // 2x2 wave grid of 64x64 quadrants
  const int lr = lane & 15;
  const int lg = lane >> 4;

  // ---- A DMA geometry: 2 sites; chunk = s*256+tid -> row = s*64+(tid>>2),
  //      cphys = tid&3; BK=32 -> 4 chunks/row; swizzle uses (row&7) folded
  //      into the 4-chunk space: clog = cphys ^ (row&3) keeps both-sides
  //      bijective within a row (4 chunks), banks <=2-way on read (free).
  const short* agp[2];
#pragma unroll
  for (int s = 0; s < 2; s++) {
    int row  = s * 64 + (tid >> 2);
    int clog = (tid & 3) ^ (row & 3);
    agp[s] = inpb + (size_t)toks[row] * INF + clog * 8;
  }

  // ---- B DMA geometry (identical pattern) ----
  const short* Wbase = wbf + ((size_t)e * OUTF + (size_t)nt * BN) * INF;
  const short* bgp[2];
#pragma unroll
  for (int s = 0; s < 2; s++) {
    int row  = s * 64 + (tid >> 2);
    int clog = (tid & 3) ^ (row & 3);
    bgp[s] = Wbase + (size_t)row * INF + clog * 8;
  }

  f32x4 acc[4][4];
#pragma unroll
  for (int i = 0; i < 4; i++)
#pragma unroll
    for (int j = 0; j < 4; j++) acc[i][j] = (f32x4)0.0f;

#define DMA(t_)                                                               \
  {                                                                           \
    char* ab_ = (char*)Albs[(t_) % 3];                                        \
    char* bb_ = (char*)Blbs[(t_) % 3];                                        \
    gload16(agp[0] + (t_) * BK, ab_ + tid * 16);                              \
    gload16(agp[1] + (t_) * BK, ab_ + 4096 + tid * 16);                       \
    gload16(bgp[0] + (t_) * BK, bb_ + tid * 16);                              \
    gload16(bgp[1] + (t_) * BK, bb_ + 4096 + tid * 16);                       \
  }
#define COMP(t_)                                                              \
  {                                                                           \
    const char* ab_ = (const char*)Albs[(t_) % 3];                            \
    const char* bb_ = (const char*)Blbs[(t_) % 3];                            \
    bfrag af[4], bv[4];                                                       \
    _Pragma("unroll") for (int i = 0; i < 4; i++) {                           \
      int row = wr * 64 + i * 16 + lr;                                        \
      int c = lg ^ (row & 3);                                                 \
      af[i] = *(const bfrag*)(ab_ + row * 64 + c * 16);                       \
    }                                                                         \
    _Pragma("unroll") for (int j = 0; j < 4; j++) {                           \
      int row = wc * 64 + j * 16 + lr;                                        \
      int c = lg ^ (row & 3);                                                 \
      bv[j] = *(const bfrag*)(bb_ + row * 64 + c * 16);                       \
    }                                                                         \
    _Pragma("unroll") for (int i = 0; i < 4; i++)                             \
      _Pragma("unroll") for (int j = 0; j < 4; j++)                           \
          acc[i][j] = __builtin_amdgcn_mfma_f32_16x16x32_bf16(                \
              af[i], bv[j], acc[i][j], 0, 0, 0);                              \
  }

  // ---- prologue: slots 0,1 in flight; retire slot 0 (R8-proven pattern) ----
  DMA(0);
  DMA(1);
  KBAR(4)

#pragma unroll
  for (int t = 0; t < NST; t++) {
    if (t + 2 < NST) DMA(t + 2);   // rides across the barrier
    COMP(t);
    if (t + 2 < NST) {
      KBAR(4)      // retires DMA(t+1); DMA(t+2) stays in flight
    } else if (t + 1 < NST) {
      KBAR(0)      // drain DMA(NST-1)
    }
  }

  // ---- epilogue: C/D col=lane&15, row=(lane>>4)*4+reg (R4-proven) ----
#pragma unroll
  for (int i = 0; i < 4; i++) {
    int rbase = wr * 64 + i * 16 + lg * 4;
#pragma unroll
    for (int r = 0; r < 4; r++) {
      int rr = rbase + r;
      if (rr < m_valid) {
        float* orow = out + (size_t)toks[rr] * OUTF + (size_t)nt * BN +
                      (size_t)wc * 64 + lr;
#pragma unroll
        for (int j = 0; j < 4; j++) orow[j * 16] = acc[i][j][r];
      }
    }
  }
#undef DMA
#undef COMP
}

extern "C" void kernel_launch(void* const* d_in, const int* in_sizes, int n_in,
                              void* d_out, int out_size, void* d_ws, size_t ws_size,
                              hipStream_t stream) {
  (void)in_sizes; (void)n_in; (void)out_size; (void)ws_size;
  const float* inp    = (const float*)d_in[0];
  const int*   gate   = (const int*)d_in[1];
  const float* weight = (const float*)d_in[2];
  float* out = (float*)d_out;

  char* ws = (char*)d_ws;
  int*   cursor = (int*)ws;                    // 64 B
  int*   perm   = (int*)(ws + 4096);           // 8*2560*4 = 80 KB
  short* wbf    = (short*)(ws + (1 << 20));    // 4 MB bf16 weight
  short* inpb   = (short*)(ws + (8 << 20));    // 16.7 MB bf16 inp (token order)

  hipMemsetAsync(cursor, 0, 64, stream);
  k_prep<<<1088 + (TOKENS * INF) / (256 * 8), 256, 0, stream>>>(
      gate, cursor, perm, weight, (s8v*)wbf, inp, (s8v*)inpb);
  moe_gemm11<<<NEXP * 4 * MAXMT, 256, 0, stream>>>(inpb, wbf, cursor, perm, out);
}

// Round 18
// 34.943 us; speedup vs baseline: 1.1269x; 1.1269x over previous
//
#include <hip/hip_runtime.h>
#include <hip/hip_bf16.h>

#define TOKENS 16384
#define NEXP 8
#define INF 512
#define OUTF 512

#define BM 64
#define BN 128
#define BK 64
#define NST (INF / BK)     // 8 K-steps
#define MAXMT 40           // 2560 rows/expert; counts ~2048±42(σ) -> +12σ safe
#define EROWS (MAXMT * BM)

using f32x4 = __attribute__((ext_vector_type(4))) float;
using bfrag = __attribute__((ext_vector_type(8))) __bf16;
using s8v   = __attribute__((ext_vector_type(8))) short;

// fp32 -> bf16 RNE
__device__ __forceinline__ short f2bf(float f) {
  union { float f; unsigned u; } v; v.f = f;
  unsigned r = v.u + 0x7fffu + ((v.u >> 16) & 1u);
  return (short)(r >> 16);
}

__device__ __forceinline__ void gload16(const void* g, void* l) {
  __builtin_amdgcn_global_load_lds(
      (const __attribute__((address_space(1))) unsigned int*)g,
      (__attribute__((address_space(3))) unsigned int*)l, 16, 0, 0);
}

__device__ __forceinline__ s8v pack8(float4 a, float4 b) {
  s8v p;
  p[0] = f2bf(a.x); p[1] = f2bf(a.y); p[2] = f2bf(a.z); p[3] = f2bf(a.w);
  p[4] = f2bf(b.x); p[5] = f2bf(b.y); p[6] = f2bf(b.z); p[7] = f2bf(b.w);
  return p;
}

__device__ __forceinline__ bfrag cvt8(f32x4 lo, f32x4 hi) {
  bfrag r;
  r[0] = (__bf16)lo[0]; r[1] = (__bf16)lo[1];
  r[2] = (__bf16)lo[2]; r[3] = (__bf16)lo[3];
  r[4] = (__bf16)hi[0]; r[5] = (__bf16)hi[1];
  r[6] = (__bf16)hi[2]; r[7] = (__bf16)hi[3];
  return r;
}

__global__ void k_zero(int* __restrict__ cursor) {
  if (threadIdx.x < NEXP) cursor[threadIdx.x] = 0;
}

// Fused: blocks 0..63 scatter tokens by expert; blocks 64..1087 convert
// weight fp32 -> bf16 (contiguous [E][O][I]).
__global__ void k_prep(const int* __restrict__ gate, int* __restrict__ cursor,
                       int* __restrict__ perm, const float* __restrict__ w,
                       s8v* __restrict__ wb) {
  __shared__ int lc[NEXP], lb[NEXP];
  const int bid = blockIdx.x, tid = threadIdx.x;
  if (bid < 64) {
    if (tid < NEXP) lc[tid] = 0;
    __syncthreads();
    int t = bid * 256 + tid;
    int e = gate[t];
    int ls = atomicAdd(&lc[e], 1);
    __syncthreads();
    if (tid < NEXP) lb[tid] = lc[tid] ? atomicAdd(&cursor[tid], lc[tid]) : 0;
    __syncthreads();
    perm[e * EROWS + lb[e] + ls] = t;
  } else {
    int idx = (bid - 64) * 256 + tid;
    const float4* src = (const float4*)w + (size_t)idx * 2;
    wb[idx] = pack8(src[0], src[1]);
  }
}

// Grouped GEMM (champion, R11 verbatim): 64x128 tile, ~1024 active blocks
// (4/CU, 16 waves/CU), 1-phase single-buffer, plain __syncthreads (no manual
// waitcnt). Cross-block overlap hides the per-step drain (m114).
// bid = e + 8*(nt + 4*mt): e -> XCD (B_e L2-hot); the 4 nt-siblings of one
// A-tile dispatch back-to-back on the SAME XCD -> A re-reads are L2 hits.
// A staged fp32 (cvt8 at fragment read); B bf16 (k_prep).
// Swizzles both-sides (rule #21): A clog=c^(row&15); B clog=c^(row&7).
__global__ __launch_bounds__(256, 4)
void moe_gemm7(const float* __restrict__ inp, const short* __restrict__ wbf,
               const int* __restrict__ cursor, const int* __restrict__ perm,
               float* __restrict__ out) {
  const int bid = blockIdx.x;
  const int e  = bid & 7;
  const int nt = (bid >> 3) & 3;
  const int mt = bid >> 5;
  const int cnt = cursor[e];
  if (mt * BM >= cnt) return;
  const int m_valid = min(BM, cnt - mt * BM);
  const int* pb = perm + e * EROWS + mt * BM;

  __shared__ __align__(16) char Albs[BM * BK * 4];   // 16 KB fp32 A
  __shared__ __align__(16) char Blbs[BN * BK * 2];   // 16 KB bf16 B
  __shared__ int toks[BM];

  const int tid = threadIdx.x;
  if (tid < BM) toks[tid] = pb[(tid < m_valid) ? tid : 0];
  __syncthreads();

  const int lane = tid & 63;
  const int wid  = tid >> 6;
  const int wr = wid >> 1, wc = wid & 1;   // wave: rows wr*32..+31, cols wc*64..+63
  const int lr = lane & 15;
  const int lg = lane >> 4;

  // ---- A DMA geometry: 4 sites; chunk = s*256+tid -> row = s*16+(tid>>4),
  //      cphys = tid&15; source clog = cphys ^ (row&15); dest linear.
  const float* agp[4];
#pragma unroll
  for (int s = 0; s < 4; s++) {
    int row  = s * 16 + (tid >> 4);
    int clog = (tid & 15) ^ (row & 15);
    agp[s] = inp + (size_t)toks[row] * INF + clog * 4;
  }

  // ---- B DMA geometry: 4 sites; chunk = s*256+tid -> row = s*32+(tid>>3),
  //      cphys = tid&7; source clog = cphys ^ (row&7); dest linear.
  const short* Wbase = wbf + ((size_t)e * OUTF + (size_t)nt * BN) * INF;
  const short* bgp[4];
#pragma unroll
  for (int s = 0; s < 4; s++) {
    int row  = s * 32 + (tid >> 3);
    int clog = (tid & 7) ^ (row & 7);
    bgp[s] = Wbase + (size_t)row * INF + clog * 8;
  }

  f32x4 acc[2][4];
#pragma unroll
  for (int m = 0; m < 2; m++)
#pragma unroll
    for (int j = 0; j < 4; j++) acc[m][j] = (f32x4)0.0f;

  for (int t = 0; t < NST; t++) {
    // ---- stage tile t (8 homogeneous gload16/thread) ----
#pragma unroll
    for (int s = 0; s < 4; s++)
      gload16(agp[s] + t * BK, Albs + s * 4096 + tid * 16);
#pragma unroll
    for (int s = 0; s < 4; s++)
      gload16(bgp[s] + t * BK, Blbs + s * 4096 + tid * 16);
    __syncthreads();   // drain DMA

    // ---- compute (2 ks x 2 m x 4 n = 16 MFMA/wave) ----
#pragma unroll
    for (int ks = 0; ks < 2; ks++) {
      bfrag af[2], bv[4];
#pragma unroll
      for (int m = 0; m < 2; m++) {
        int row = wr * 32 + m * 16 + lr;
        int c0 = (ks * 8 + lg * 2) ^ (row & 15);
        int c1 = (ks * 8 + lg * 2 + 1) ^ (row & 15);
        f32x4 lo = *(const f32x4*)(Albs + row * 256 + c0 * 16);
        f32x4 hi = *(const f32x4*)(Albs + row * 256 + c1 * 16);
        af[m] = cvt8(lo, hi);
      }
#pragma unroll
      for (int j = 0; j < 4; j++) {
        int row = wc * 64 + j * 16 + lr;
        int c = (ks * 4 + lg) ^ (row & 7);
        bv[j] = *(const bfrag*)(Blbs + row * 128 + c * 16);
      }
#pragma unroll
      for (int m = 0; m < 2; m++)
#pragma unroll
        for (int j = 0; j < 4; j++)
          acc[m][j] = __builtin_amdgcn_mfma_f32_16x16x32_bf16(af[m], bv[j],
                                                              acc[m][j], 0, 0, 0);
    }
    if (t + 1 < NST) __syncthreads();  // reads done before next overwrite
  }

  // ---- epilogue: C/D col=lane&15, row=(lane>>4)*4+reg (proven) ----
#pragma unroll
  for (int m = 0; m < 2; m++) {
#pragma unroll
    for (int r = 0; r < 4; r++) {
      int rowE = wr * 32 + m * 16 + lg * 4 + r;
      if (rowE < m_valid) {
        float* orow = out + (size_t)toks[rowE] * OUTF + (size_t)nt * BN +
                      (size_t)wc * 64 + lr;
#pragma unroll
        for (int j = 0; j < 4; j++) orow[j * 16] = acc[m][j][r];
      }
    }
  }
}

extern "C" void kernel_launch(void* const* d_in, const int* in_sizes, int n_in,
                              void* d_out, int out_size, void* d_ws, size_t ws_size,
                              hipStream_t stream) {
  (void)in_sizes; (void)n_in; (void)out_size; (void)ws_size;
  const float* inp    = (const float*)d_in[0];
  const int*   gate   = (const int*)d_in[1];
  const float* weight = (const float*)d_in[2];
  float* out = (float*)d_out;

  char* ws = (char*)d_ws;
  int*   cursor = (int*)ws;                    // 64 B
  int*   perm   = (int*)(ws + 4096);           // 8*2560*4 = 80 KB
  short* wbf    = (short*)(ws + (1 << 20));    // 4 MB bf16 weight

  k_zero<<<1, 64, 0, stream>>>(cursor);
  k_prep<<<64 + (NEXP * OUTF * INF) / (256 * 8), 256, 0, stream>>>(
      gate, cursor, perm, weight, (s8v*)wbf);
  moe_gemm7<<<NEXP * 4 * MAXMT, 256, 0, stream>>>(inp, wbf, cursor, perm, out);
}